// Round 10
// baseline (329.987 us; speedup 1.0000x reference)
//
#include <hip/hip_runtime.h>

#define F_IN 512
#define HDIM 64
#define NCLS 40
#define NLAYER 4
#define EPS_F 0.2f

typedef __attribute__((ext_vector_type(8))) short short8;
typedef __attribute__((ext_vector_type(4))) float f32x4;
typedef __attribute__((ext_vector_type(8))) unsigned short ushort8;
typedef unsigned long long u64;

__device__ __forceinline__ unsigned short f2bf(float f) {
  unsigned u = __float_as_uint(f);
  u += 0x7FFFu + ((u >> 16) & 1u);  // RNE
  return (unsigned short)(u >> 16);
}
__device__ __forceinline__ float bf2f(unsigned short s) {
  return __uint_as_float(((unsigned)s) << 16);
}

// ---------------- CSR build ----------------
__global__ __launch_bounds__(256) void k_init(int* indeg, int nN) {
  int i = blockIdx.x * 256 + threadIdx.x;
  if (i < nN) indeg[i] = 0;
}

// histogram; the atomic's return value is the edge's rank within its dst row
__global__ __launch_bounds__(256) void k_hist(const int* __restrict__ dst, int* indeg,
                                              int* __restrict__ rank, int nE) {
  int e = blockIdx.x * 256 + threadIdx.x;
  if (e < nE) rank[e] = atomicAdd(&indeg[dst[e]], 1);
}

__global__ __launch_bounds__(256) void k_bsum(const int* __restrict__ indeg, int* bsum, int nN) {
  int i0 = blockIdx.x * 512 + threadIdx.x;
  int v = 0;
  if (i0 < nN) v += indeg[i0];
  if (i0 + 256 < nN) v += indeg[i0 + 256];
#pragma unroll
  for (int off = 32; off > 0; off >>= 1) v += __shfl_xor(v, off, 64);
  __shared__ int s[4];
  if ((threadIdx.x & 63) == 0) s[threadIdx.x >> 6] = v;
  __syncthreads();
  if (threadIdx.x == 0) bsum[blockIdx.x] = s[0] + s[1] + s[2] + s[3];
}

__global__ __launch_bounds__(128) void k_bscan(const int* __restrict__ bsum, int* bpre,
                                               int* rowptr, int nblk, int nN, int nE) {
  __shared__ int sb[128];
  int t = threadIdx.x;
  int v = (t < nblk) ? bsum[t] : 0;
  sb[t] = v;
  __syncthreads();
  int acc = v;
  for (int off = 1; off < 128; off <<= 1) {
    int o = (t >= off) ? sb[t - off] : 0;
    __syncthreads();
    acc += o;
    sb[t] = acc;
    __syncthreads();
  }
  if (t < nblk) bpre[t] = acc - v;
  if (t == 0) rowptr[nN] = nE;
}

// per-chunk scan -> rowptr ; fused per-node finish (P0, Q0, selfc0) from lin1's al/ar
__global__ __launch_bounds__(512) void k_rowptr(const int* __restrict__ indeg,
                                                const int* __restrict__ bpre,
                                                const float* __restrict__ al,
                                                const float* __restrict__ ar,
                                                int* rowptr,
                                                float2* P, float2* Q, float* selfc, int nN) {
  __shared__ int sb[512];
  int t = threadIdx.x;
  int i = blockIdx.x * 512 + t;
  int v = (i < nN) ? indeg[i] : 0;
  sb[t] = v;
  __syncthreads();
  int acc = v;
  for (int off = 1; off < 512; off <<= 1) {
    int o = (t >= off) ? sb[t - off] : 0;
    __syncthreads();
    acc += o;
    sb[t] = acc;
    __syncthreads();
  }
  if (i < nN) {
    rowptr[i] = bpre[blockIdx.x] + acc - v;
    float dv = rsqrtf((float)v + 1.0f);  // +1 self-loop
    float a = al[i], r = ar[i];
    P[i] = make_float2(a, dv);
    Q[i] = make_float2(r, dv);
    selfc[i] = tanhf(a + r) * dv * dv;
  }
}

// atomic-free scatter: q = rowptr[d] + rank[e]; single 4B src store
__global__ __launch_bounds__(256) void k_scatter(const int* __restrict__ src,
                                                 const int* __restrict__ dst,
                                                 const int* __restrict__ rank,
                                                 const int* __restrict__ rowptr,
                                                 int* __restrict__ csrsrc, int nE) {
  int e = blockIdx.x * 256 + threadIdx.x;
  if (e < nE) {
    int d = dst[e];
    csrsrc[rowptr[d] + rank[e]] = src[e];
  }
}

// ---------------- lin1: hraw = bf16(relu(x @ W1^T + b1)), feature-split planes, fused L0 scores ----------------
__global__ __launch_bounds__(256) void k_lin1(const float* __restrict__ x,
                                              const float* __restrict__ W1,
                                              const float* __restrict__ b1,
                                              const float* __restrict__ attl0,
                                              const float* __restrict__ attr0,
                                              unsigned short* __restrict__ hraw,
                                              float* __restrict__ al, float* __restrict__ ar,
                                              int nN) {
  __shared__ unsigned short xs[64 * 64];
  __shared__ unsigned short ws[64 * 64];
  const int t = threadIdx.x;
  const int wv = t >> 6;
  const int l = t & 63;
  const int n0 = blockIdx.x * 64;
  const int srow = t >> 2;
  const int sk4 = (t & 3) * 4;
  const bool xvalid = (n0 + srow) < nN;
  const f32x4* x4 = reinterpret_cast<const f32x4*>(x);
  const f32x4* w4 = reinterpret_cast<const f32x4*>(W1);
  short8* xs8 = reinterpret_cast<short8*>(xs);
  short8* ws8 = reinterpret_cast<short8*>(ws);
  const int wslot0 = srow * 8 + (((t & 3) * 2 + 0) ^ (srow & 7));
  const int wslot1 = srow * 8 + (((t & 3) * 2 + 1) ^ (srow & 7));
  const int arow = l & 15;
  const int kgrp = l >> 4;
  const size_t PL = (size_t)nN * 32;
  f32x4 acc[4] = {{0.f, 0.f, 0.f, 0.f},
                  {0.f, 0.f, 0.f, 0.f},
                  {0.f, 0.f, 0.f, 0.f},
                  {0.f, 0.f, 0.f, 0.f}};
  f32x4 xa[4], wa[4];
  const f32x4 zero4 = {0.f, 0.f, 0.f, 0.f};
  {
    const size_t xb = (size_t)(n0 + srow) * (F_IN / 4) + sk4;
    const size_t wb = (size_t)srow * (F_IN / 4) + sk4;
#pragma unroll
    for (int r = 0; r < 4; ++r) {
      xa[r] = xvalid ? x4[xb + r] : zero4;
      wa[r] = w4[wb + r];
    }
  }
  for (int c = 0; c < 8; ++c) {
    short8 p0, p1, q0, q1;
#pragma unroll
    for (int r = 0; r < 2; ++r) {
#pragma unroll
      for (int j = 0; j < 4; ++j) {
        p0[r * 4 + j] = (short)f2bf(xa[r][j]);
        p1[r * 4 + j] = (short)f2bf(xa[2 + r][j]);
        q0[r * 4 + j] = (short)f2bf(wa[r][j]);
        q1[r * 4 + j] = (short)f2bf(wa[2 + r][j]);
      }
    }
    xs8[wslot0] = p0;
    xs8[wslot1] = p1;
    ws8[wslot0] = q0;
    ws8[wslot1] = q1;
    __syncthreads();
    if (c < 7) {
      const size_t xb = (size_t)(n0 + srow) * (F_IN / 4) + (c + 1) * 16 + sk4;
      const size_t wb = (size_t)srow * (F_IN / 4) + (c + 1) * 16 + sk4;
#pragma unroll
      for (int r = 0; r < 4; ++r) {
        xa[r] = xvalid ? x4[xb + r] : zero4;
        wa[r] = w4[wb + r];
      }
    }
#pragma unroll
    for (int c2 = 0; c2 < 2; ++c2) {
      const short8 a = xs8[(wv * 16 + arow) * 8 + ((c2 * 4 + kgrp) ^ (arow & 7))];
#pragma unroll
      for (int fs = 0; fs < 4; ++fs) {
        const short8 b = ws8[(fs * 16 + arow) * 8 + ((c2 * 4 + kgrp) ^ (arow & 7))];
        acc[fs] = __builtin_amdgcn_mfma_f32_16x16x32_bf16(a, b, acc[fs], 0, 0, 0);
      }
    }
    __syncthreads();
  }
  // epilogue: relu+bias, bf16 store into feature-split planes, fused layer-0 scores
  float psl[4] = {0.f, 0.f, 0.f, 0.f};
  float psr[4] = {0.f, 0.f, 0.f, 0.f};
#pragma unroll
  for (int fs = 0; fs < 4; ++fs) {
    const int feat = fs * 16 + arow;
    const float bias = b1[feat];
    const float atl = attl0[feat];
    const float atr = attr0[feat];
    const size_t pbase = (size_t)(fs >> 1) * PL + (size_t)((fs & 1) * 16 + arow);
#pragma unroll
    for (int j = 0; j < 4; ++j) {
      const float v = fmaxf(acc[fs][j] + bias, 0.f);
      const int node = n0 + wv * 16 + kgrp * 4 + j;
      if (node < nN) hraw[pbase + (size_t)node * 32] = f2bf(v);
      psl[j] = fmaf(v, atl, psl[j]);
      psr[j] = fmaf(v, atr, psr[j]);
    }
  }
#pragma unroll
  for (int off = 1; off <= 8; off <<= 1) {
#pragma unroll
    for (int j = 0; j < 4; ++j) {
      psl[j] += __shfl_xor(psl[j], off, 64);
      psr[j] += __shfl_xor(psr[j], off, 64);
    }
  }
  if (arow == 0) {
#pragma unroll
    for (int j = 0; j < 4; ++j) {
      const int node = n0 + wv * 16 + kgrp * 4 + j;
      if (node < nN) {
        al[node] = psl[j];
        ar[node] = psr[j];
      }
    }
  }
}

// ---------------- fused coef+aggregation over one feature plane ----------------
// 16 edge-groups x 4 lanes x 64B gathers; coef computed inline from P[s],Q[d].
// PASS 0 stores partial next-layer scores to scratch; PASS 1 finishes into Pn/Qn/Sn.
template <int PASS, bool WNEXT>
__global__ __launch_bounds__(256) void k_agg(const unsigned short* __restrict__ hin_p,
                                             const unsigned short* __restrict__ hraw_p,
                                             const int* __restrict__ rowptr,
                                             const int* __restrict__ csrsrc,
                                             const float2* __restrict__ Pc,
                                             const float2* __restrict__ Qc,
                                             const float* __restrict__ Sc,
                                             const float* __restrict__ attl_h,
                                             const float* __restrict__ attr_h,
                                             float* __restrict__ psl_s, float* __restrict__ psr_s,
                                             float2* __restrict__ Pn, float2* __restrict__ Qn,
                                             float* __restrict__ Sn,
                                             unsigned short* __restrict__ hout_p, int nN) {
  const int wid = threadIdx.x >> 6, lane = threadIdx.x & 63;
  const int d = blockIdx.x * 4 + wid;
  if (d >= nN) return;
  const int grp = lane >> 2;        // edge slot 0..15
  const int fo = (lane & 3) * 8;    // feature 0,8,16,24 within the 32-plane
  const size_t base = (size_t)d * 32 + fo;
  const float2 qd = Qc[d];  // {ar_d, dinv_d}
  float acc[8] = {};
  if (grp == 0) {
    const float sc = Sc[d];
    const ushort8 hd = *reinterpret_cast<const ushort8*>(&hin_p[base]);
    const ushort8 rw = *reinterpret_cast<const ushort8*>(&hraw_p[base]);
#pragma unroll
    for (int j = 0; j < 8; ++j) acc[j] = fmaf(bf2f(hd[j]), sc, EPS_F * bf2f(rw[j]));
  }
  const int r1 = rowptr[d + 1];
  for (int e = rowptr[d] + grp; e < r1; e += 16) {
    const int s = csrsrc[e];
    const float2 p = Pc[s];  // {al_s, dinv_s}
    const ushort8 hv = *reinterpret_cast<const ushort8*>(&hin_p[(size_t)s * 32 + fo]);
    const float c = tanhf(p.x + qd.x) * (p.y * qd.y);
#pragma unroll
    for (int j = 0; j < 8; ++j) acc[j] = fmaf(bf2f(hv[j]), c, acc[j]);
  }
  // reduce across 16 edge-groups (lanes sharing lane&3 hold same feats)
#pragma unroll
  for (int off = 4; off <= 32; off <<= 1) {
#pragma unroll
    for (int j = 0; j < 8; ++j) acc[j] += __shfl_xor(acc[j], off, 64);
  }
  if (grp == 0) {
    ushort8 o;
#pragma unroll
    for (int j = 0; j < 8; ++j) o[j] = f2bf(acc[j]);
    *reinterpret_cast<ushort8*>(&hout_p[base]) = o;
  }
  if (WNEXT) {
    float psl = 0.f, psr = 0.f;
#pragma unroll
    for (int j = 0; j < 8; ++j) {
      psl = fmaf(acc[j], attl_h[fo + j], psl);
      psr = fmaf(acc[j], attr_h[fo + j], psr);
    }
    psl += __shfl_xor(psl, 1, 64);
    psl += __shfl_xor(psl, 2, 64);
    psr += __shfl_xor(psr, 1, 64);
    psr += __shfl_xor(psr, 2, 64);
    if (lane == 0) {
      if (PASS == 0) {
        psl_s[d] = psl;
        psr_s[d] = psr;
      } else {
        psl += psl_s[d];
        psr += psr_s[d];
        Pn[d] = make_float2(psl, qd.y);
        Qn[d] = make_float2(psr, qd.y);
        Sn[d] = tanhf(psl + psr) * qd.y * qd.y;
      }
    }
  }
}

// ---------------- output: thread-per-node logits + log_softmax (two planes) ----------------
__global__ __launch_bounds__(256) void k_out(const unsigned short* __restrict__ h,
                                             const float* __restrict__ W2,
                                             const float* __restrict__ b2,
                                             float* __restrict__ out, int nN) {
  __shared__ float w2s[NCLS * HDIM];  // [c][j] row-major
  __shared__ float b2s[NCLS];
  for (int i = threadIdx.x; i < NCLS * HDIM; i += 256) w2s[i] = W2[i];
  if (threadIdx.x < NCLS) b2s[threadIdx.x] = b2[threadIdx.x];
  __syncthreads();
  const int n = blockIdx.x * 256 + threadIdx.x;
  if (n >= nN) return;
  const size_t PL = (size_t)nN * 32;
  float hr[HDIM];
  const ushort8* lo = reinterpret_cast<const ushort8*>(&h[(size_t)n * 32]);
  const ushort8* hi = reinterpret_cast<const ushort8*>(&h[PL + (size_t)n * 32]);
#pragma unroll
  for (int r = 0; r < 4; ++r) {
    const ushort8 v = lo[r];
#pragma unroll
    for (int j = 0; j < 8; ++j) hr[r * 8 + j] = bf2f(v[j]);
  }
#pragma unroll
  for (int r = 0; r < 4; ++r) {
    const ushort8 v = hi[r];
#pragma unroll
    for (int j = 0; j < 8; ++j) hr[32 + r * 8 + j] = bf2f(v[j]);
  }
  const float4* w2s4 = reinterpret_cast<const float4*>(w2s);
  float logits[NCLS];
  float m = -INFINITY;
#pragma unroll
  for (int c = 0; c < NCLS; ++c) {
    float a0 = 0.f, a1 = 0.f, a2 = 0.f, a3 = 0.f;
#pragma unroll
    for (int j4 = 0; j4 < HDIM / 4; j4 += 4) {
      const float4 w0 = w2s4[c * (HDIM / 4) + j4 + 0];
      const float4 w1 = w2s4[c * (HDIM / 4) + j4 + 1];
      const float4 w2v = w2s4[c * (HDIM / 4) + j4 + 2];
      const float4 w3 = w2s4[c * (HDIM / 4) + j4 + 3];
      const int j = j4 * 4;
      a0 = fmaf(hr[j + 0], w0.x, a0);  a0 = fmaf(hr[j + 1], w0.y, a0);
      a0 = fmaf(hr[j + 2], w0.z, a0);  a0 = fmaf(hr[j + 3], w0.w, a0);
      a1 = fmaf(hr[j + 4], w1.x, a1);  a1 = fmaf(hr[j + 5], w1.y, a1);
      a1 = fmaf(hr[j + 6], w1.z, a1);  a1 = fmaf(hr[j + 7], w1.w, a1);
      a2 = fmaf(hr[j + 8], w2v.x, a2); a2 = fmaf(hr[j + 9], w2v.y, a2);
      a2 = fmaf(hr[j + 10], w2v.z, a2); a2 = fmaf(hr[j + 11], w2v.w, a2);
      a3 = fmaf(hr[j + 12], w3.x, a3); a3 = fmaf(hr[j + 13], w3.y, a3);
      a3 = fmaf(hr[j + 14], w3.z, a3); a3 = fmaf(hr[j + 15], w3.w, a3);
    }
    const float lg = (a0 + a1) + (a2 + a3) + b2s[c];
    logits[c] = lg;
    m = fmaxf(m, lg);
  }
  float s = 0.f;
#pragma unroll
  for (int c = 0; c < NCLS; ++c) s += expf(logits[c] - m);
  const float lse = m + logf(s);
  float4* o4 = reinterpret_cast<float4*>(&out[(size_t)n * NCLS]);
#pragma unroll
  for (int c4 = 0; c4 < NCLS / 4; ++c4) {
    float4 o;
    o.x = logits[c4 * 4 + 0] - lse;
    o.y = logits[c4 * 4 + 1] - lse;
    o.z = logits[c4 * 4 + 2] - lse;
    o.w = logits[c4 * 4 + 3] - lse;
    o4[c4] = o;
  }
}

extern "C" void kernel_launch(void* const* d_in, const int* in_sizes, int n_in,
                              void* d_out, int out_size, void* d_ws, size_t ws_size,
                              hipStream_t stream) {
  const float* x = (const float*)d_in[0];
  const int* ei = (const int*)d_in[1];
  const float* W1 = (const float*)d_in[2];
  const float* b1 = (const float*)d_in[3];
  const float* W2 = (const float*)d_in[4];
  const float* b2 = (const float*)d_in[5];
  const float* attl = (const float*)d_in[6];
  const float* attr = (const float*)d_in[7];
  float* out = (float*)d_out;

  const int nN = in_sizes[0] / F_IN;
  const int nE = in_sizes[1] / 2;
  const int* src = ei;
  const int* dst = ei + nE;
  const size_t PL = (size_t)nN * 32;

  char* w = (char*)d_ws;
  size_t off = 0;
  auto alloc = [&](size_t bytes) {
    void* p = (void*)(w + off);
    off = (off + bytes + 255) & ~(size_t)255;
    return p;
  };
  unsigned short* hraw = (unsigned short*)alloc((size_t)nN * HDIM * 2);
  unsigned short* hA = (unsigned short*)alloc((size_t)nN * HDIM * 2);
  unsigned short* hB = (unsigned short*)alloc((size_t)nN * HDIM * 2);
  float2* P0 = (float2*)alloc((size_t)nN * 8);
  float2* Q0 = (float2*)alloc((size_t)nN * 8);
  float* S0 = (float*)alloc((size_t)nN * 4);
  float2* P1 = (float2*)alloc((size_t)nN * 8);
  float2* Q1 = (float2*)alloc((size_t)nN * 8);
  float* S1 = (float*)alloc((size_t)nN * 4);
  float* al = (float*)alloc((size_t)nN * 4);
  float* ar = (float*)alloc((size_t)nN * 4);
  int* indeg = (int*)alloc((size_t)nN * 4);
  int* rank = (int*)alloc((size_t)nE * 4);
  int* rowptr = (int*)alloc((size_t)(nN + 1) * 4);
  int* csrsrc = (int*)alloc((size_t)nE * 4);
  int* bsum = (int*)alloc(1024);
  int* bpre = (int*)alloc(1024);

  const int nb_n = (nN + 255) / 256;
  const int nb_e = (nE + 255) / 256;
  const int nblk = (nN + 511) / 512;  // 98 <= 128
  const int nb4 = (nN + 3) / 4;

  // lin1 first (independent of graph), fused layer-0 scores
  k_lin1<<<(nN + 63) / 64, 256, 0, stream>>>(x, W1, b1, attl, attr, hraw, al, ar, nN);
  // CSR build (atomic-free scatter, 4B payload)
  k_init<<<nb_n, 256, 0, stream>>>(indeg, nN);
  k_hist<<<nb_e, 256, 0, stream>>>(dst, indeg, rank, nE);
  k_bsum<<<nblk, 256, 0, stream>>>(indeg, bsum, nN);
  k_bscan<<<1, 128, 0, stream>>>(bsum, bpre, rowptr, nblk, nN, nE);
  k_rowptr<<<nblk, 512, 0, stream>>>(indeg, bpre, al, ar, rowptr, P0, Q0, S0, nN);
  k_scatter<<<nb_e, 256, 0, stream>>>(src, dst, rank, rowptr, csrsrc, nE);

  const unsigned short* hin = hraw;
  unsigned short* hout = hA;
  float2 *Pc = P0, *Qc = Q0, *Pn = P1, *Qn = Q1;
  float *Sc = S0, *Sn = S1;
  for (int l = 0; l < NLAYER; ++l) {
    const float* atl_n = attl + (l + 1) * HDIM;
    const float* atr_n = attr + (l + 1) * HDIM;
    if (l < NLAYER - 1) {
      k_agg<0, true><<<nb4, 256, 0, stream>>>(hin, hraw, rowptr, csrsrc, Pc, Qc, Sc,
                                              atl_n, atr_n, al, ar, Pn, Qn, Sn, hout, nN);
      k_agg<1, true><<<nb4, 256, 0, stream>>>(hin + PL, hraw + PL, rowptr, csrsrc, Pc, Qc, Sc,
                                              atl_n + 32, atr_n + 32, al, ar, Pn, Qn, Sn,
                                              hout + PL, nN);
    } else {
      k_agg<0, false><<<nb4, 256, 0, stream>>>(hin, hraw, rowptr, csrsrc, Pc, Qc, Sc,
                                               nullptr, nullptr, al, ar, Pn, Qn, Sn, hout, nN);
      k_agg<1, false><<<nb4, 256, 0, stream>>>(hin + PL, hraw + PL, rowptr, csrsrc, Pc, Qc, Sc,
                                               nullptr, nullptr, al, ar, Pn, Qn, Sn,
                                               hout + PL, nN);
    }
    hin = hout;
    hout = (hout == hA) ? hB : hA;
    float2* tp = Pc; Pc = Pn; Pn = tp;
    float2* tq = Qc; Qc = Qn; Qn = tq;
    float* ts = Sc; Sc = Sn; Sn = ts;
  }
  k_out<<<nb_n, 256, 0, stream>>>(hin, W2, b2, out, nN);
}

// Round 11
// 238.221 us; speedup vs baseline: 1.3852x; 1.3852x over previous
//
#include <hip/hip_runtime.h>

#define F_IN 512
#define HDIM 64
#define NCLS 40
#define NLAYER 4
#define EPS_F 0.2f

typedef __attribute__((ext_vector_type(8))) short short8;
typedef __attribute__((ext_vector_type(4))) float f32x4;
typedef __attribute__((ext_vector_type(8))) unsigned short ushort8;
typedef unsigned long long u64;

__device__ __forceinline__ unsigned short f2bf(float f) {
  unsigned u = __float_as_uint(f);
  u += 0x7FFFu + ((u >> 16) & 1u);  // RNE
  return (unsigned short)(u >> 16);
}
__device__ __forceinline__ float bf2f(unsigned short s) {
  return __uint_as_float(((unsigned)s) << 16);
}

// ---------------- CSR build ----------------
__global__ __launch_bounds__(256) void k_init(int* indeg, int nN) {
  int i = blockIdx.x * 256 + threadIdx.x;
  if (i < nN) indeg[i] = 0;
}

// histogram; the atomic's return value is the edge's rank within its dst row
__global__ __launch_bounds__(256) void k_hist(const int* __restrict__ dst, int* indeg,
                                              int* __restrict__ rank, int nE) {
  int e = blockIdx.x * 256 + threadIdx.x;
  if (e < nE) rank[e] = atomicAdd(&indeg[dst[e]], 1);
}

__global__ __launch_bounds__(256) void k_bsum(const int* __restrict__ indeg, int* bsum, int nN) {
  int i0 = blockIdx.x * 512 + threadIdx.x;
  int v = 0;
  if (i0 < nN) v += indeg[i0];
  if (i0 + 256 < nN) v += indeg[i0 + 256];
#pragma unroll
  for (int off = 32; off > 0; off >>= 1) v += __shfl_xor(v, off, 64);
  __shared__ int s[4];
  if ((threadIdx.x & 63) == 0) s[threadIdx.x >> 6] = v;
  __syncthreads();
  if (threadIdx.x == 0) bsum[blockIdx.x] = s[0] + s[1] + s[2] + s[3];
}

__global__ __launch_bounds__(128) void k_bscan(const int* __restrict__ bsum, int* bpre,
                                               int* rowptr, int nblk, int nN, int nE) {
  __shared__ int sb[128];
  int t = threadIdx.x;
  int v = (t < nblk) ? bsum[t] : 0;
  sb[t] = v;
  __syncthreads();
  int acc = v;
  for (int off = 1; off < 128; off <<= 1) {
    int o = (t >= off) ? sb[t - off] : 0;
    __syncthreads();
    acc += o;
    sb[t] = acc;
    __syncthreads();
  }
  if (t < nblk) bpre[t] = acc - v;
  if (t == 0) rowptr[nN] = nE;
}

// per-chunk scan -> rowptr ; fused per-node finish (P0, Q0, S0) from lin1's al/ar
__global__ __launch_bounds__(512) void k_rowptr(const int* __restrict__ indeg,
                                                const int* __restrict__ bpre,
                                                const float* __restrict__ al,
                                                const float* __restrict__ ar,
                                                int* rowptr,
                                                float2* P, float2* Q, float* selfc, int nN) {
  __shared__ int sb[512];
  int t = threadIdx.x;
  int i = blockIdx.x * 512 + t;
  int v = (i < nN) ? indeg[i] : 0;
  sb[t] = v;
  __syncthreads();
  int acc = v;
  for (int off = 1; off < 512; off <<= 1) {
    int o = (t >= off) ? sb[t - off] : 0;
    __syncthreads();
    acc += o;
    sb[t] = acc;
    __syncthreads();
  }
  if (i < nN) {
    rowptr[i] = bpre[blockIdx.x] + acc - v;
    float dv = rsqrtf((float)v + 1.0f);  // +1 self-loop
    float a = al[i], r = ar[i];
    P[i] = make_float2(a, dv);
    Q[i] = make_float2(r, dv);
    selfc[i] = tanhf(a + r) * dv * dv;
  }
}

// atomic-free scatter: q = rowptr[d] + rank[e]; single 4B src store
__global__ __launch_bounds__(256) void k_scatter(const int* __restrict__ src,
                                                 const int* __restrict__ dst,
                                                 const int* __restrict__ rank,
                                                 const int* __restrict__ rowptr,
                                                 int* __restrict__ csrsrc, int nE) {
  int e = blockIdx.x * 256 + threadIdx.x;
  if (e < nE) {
    int d = dst[e];
    csrsrc[rowptr[d] + rank[e]] = src[e];
  }
}

// ---------------- lin1: hraw = bf16(relu(x @ W1^T + b1)) via bf16 MFMA, fused layer-0 scores ----------------
__global__ __launch_bounds__(256) void k_lin1(const float* __restrict__ x,
                                              const float* __restrict__ W1,
                                              const float* __restrict__ b1,
                                              const float* __restrict__ attl0,
                                              const float* __restrict__ attr0,
                                              unsigned short* __restrict__ hraw,
                                              float* __restrict__ al, float* __restrict__ ar,
                                              int nN) {
  __shared__ unsigned short xs[64 * 64];
  __shared__ unsigned short ws[64 * 64];
  const int t = threadIdx.x;
  const int wv = t >> 6;
  const int l = t & 63;
  const int n0 = blockIdx.x * 64;
  const int srow = t >> 2;
  const int sk4 = (t & 3) * 4;
  const bool xvalid = (n0 + srow) < nN;
  const f32x4* x4 = reinterpret_cast<const f32x4*>(x);
  const f32x4* w4 = reinterpret_cast<const f32x4*>(W1);
  short8* xs8 = reinterpret_cast<short8*>(xs);
  short8* ws8 = reinterpret_cast<short8*>(ws);
  const int wslot0 = srow * 8 + (((t & 3) * 2 + 0) ^ (srow & 7));
  const int wslot1 = srow * 8 + (((t & 3) * 2 + 1) ^ (srow & 7));
  const int arow = l & 15;
  const int kgrp = l >> 4;
  f32x4 acc[4] = {{0.f, 0.f, 0.f, 0.f},
                  {0.f, 0.f, 0.f, 0.f},
                  {0.f, 0.f, 0.f, 0.f},
                  {0.f, 0.f, 0.f, 0.f}};
  f32x4 xa[4], wa[4];
  const f32x4 zero4 = {0.f, 0.f, 0.f, 0.f};
  {
    const size_t xb = (size_t)(n0 + srow) * (F_IN / 4) + sk4;
    const size_t wb = (size_t)srow * (F_IN / 4) + sk4;
#pragma unroll
    for (int r = 0; r < 4; ++r) {
      xa[r] = xvalid ? x4[xb + r] : zero4;
      wa[r] = w4[wb + r];
    }
  }
  for (int c = 0; c < 8; ++c) {
    short8 p0, p1, q0, q1;
#pragma unroll
    for (int r = 0; r < 2; ++r) {
#pragma unroll
      for (int j = 0; j < 4; ++j) {
        p0[r * 4 + j] = (short)f2bf(xa[r][j]);
        p1[r * 4 + j] = (short)f2bf(xa[2 + r][j]);
        q0[r * 4 + j] = (short)f2bf(wa[r][j]);
        q1[r * 4 + j] = (short)f2bf(wa[2 + r][j]);
      }
    }
    xs8[wslot0] = p0;
    xs8[wslot1] = p1;
    ws8[wslot0] = q0;
    ws8[wslot1] = q1;
    __syncthreads();
    if (c < 7) {
      const size_t xb = (size_t)(n0 + srow) * (F_IN / 4) + (c + 1) * 16 + sk4;
      const size_t wb = (size_t)srow * (F_IN / 4) + (c + 1) * 16 + sk4;
#pragma unroll
      for (int r = 0; r < 4; ++r) {
        xa[r] = xvalid ? x4[xb + r] : zero4;
        wa[r] = w4[wb + r];
      }
    }
#pragma unroll
    for (int c2 = 0; c2 < 2; ++c2) {
      const short8 a = xs8[(wv * 16 + arow) * 8 + ((c2 * 4 + kgrp) ^ (arow & 7))];
#pragma unroll
      for (int fs = 0; fs < 4; ++fs) {
        const short8 b = ws8[(fs * 16 + arow) * 8 + ((c2 * 4 + kgrp) ^ (arow & 7))];
        acc[fs] = __builtin_amdgcn_mfma_f32_16x16x32_bf16(a, b, acc[fs], 0, 0, 0);
      }
    }
    __syncthreads();
  }
  // epilogue: relu+bias, bf16 store, fused layer-0 scores
  float psl[4] = {0.f, 0.f, 0.f, 0.f};
  float psr[4] = {0.f, 0.f, 0.f, 0.f};
#pragma unroll
  for (int fs = 0; fs < 4; ++fs) {
    const int feat = fs * 16 + arow;
    const float bias = b1[feat];
    const float atl = attl0[feat];
    const float atr = attr0[feat];
#pragma unroll
    for (int j = 0; j < 4; ++j) {
      const float v = fmaxf(acc[fs][j] + bias, 0.f);
      const int node = n0 + wv * 16 + kgrp * 4 + j;
      if (node < nN) hraw[(size_t)node * HDIM + feat] = f2bf(v);
      psl[j] = fmaf(v, atl, psl[j]);
      psr[j] = fmaf(v, atr, psr[j]);
    }
  }
#pragma unroll
  for (int off = 1; off <= 8; off <<= 1) {
#pragma unroll
    for (int j = 0; j < 4; ++j) {
      psl[j] += __shfl_xor(psl[j], off, 64);
      psr[j] += __shfl_xor(psr[j], off, 64);
    }
  }
  if (arow == 0) {
#pragma unroll
    for (int j = 0; j < 4; ++j) {
      const int node = n0 + wv * 16 + kgrp * 4 + j;
      if (node < nN) {
        al[node] = psl[j];
        ar[node] = psr[j];
      }
    }
  }
}

// ---------------- fused coef+aggregation: wave/dest, 8 edge-groups x 8 lanes, bf16 gathers ----------------
// coef computed inline: c = tanh(P[s].al + Q[d].ar) * P[s].dinv * Q[d].dinv
// (8 lanes of a group compute the same tanh, but the wave covers 8 DIFFERENT edges per inst)
template <bool WNEXT>
__global__ __launch_bounds__(256) void k_agg(const unsigned short* __restrict__ h,
                                             const unsigned short* __restrict__ hraw,
                                             const int* __restrict__ rowptr,
                                             const int* __restrict__ csrsrc,
                                             const float2* __restrict__ Pc,
                                             const float2* __restrict__ Qc,
                                             const float* __restrict__ Sc,
                                             const float* __restrict__ attl_n,
                                             const float* __restrict__ attr_n,
                                             float2* __restrict__ Pn, float2* __restrict__ Qn,
                                             float* __restrict__ Sn,
                                             unsigned short* __restrict__ hout, int nN) {
  const int wid = threadIdx.x >> 6, lane = threadIdx.x & 63;
  const int d = blockIdx.x * 4 + wid;
  if (d >= nN) return;
  const int grp = lane >> 3;
  const int fo = (lane & 7) * 8;
  const size_t base = (size_t)d * HDIM + fo;
  const float2 qd = Qc[d];  // {ar_d, dinv_d}
  float acc[8] = {};
  if (grp == 0) {
    const float sc = Sc[d];
    const ushort8 hd = *reinterpret_cast<const ushort8*>(&h[base]);
    const ushort8 rw = *reinterpret_cast<const ushort8*>(&hraw[base]);
#pragma unroll
    for (int j = 0; j < 8; ++j) acc[j] = fmaf(bf2f(hd[j]), sc, EPS_F * bf2f(rw[j]));
  }
  const int e1 = rowptr[d + 1];
  int e = rowptr[d] + grp;
  for (; e + 8 < e1; e += 16) {
    const int s0 = csrsrc[e];
    const int s1 = csrsrc[e + 8];
    const float2 p0 = Pc[s0];
    const float2 p1 = Pc[s1];
    const ushort8 h0v = *reinterpret_cast<const ushort8*>(&h[(size_t)s0 * HDIM + fo]);
    const ushort8 h1v = *reinterpret_cast<const ushort8*>(&h[(size_t)s1 * HDIM + fo]);
    const float c0 = tanhf(p0.x + qd.x) * (p0.y * qd.y);
    const float c1 = tanhf(p1.x + qd.x) * (p1.y * qd.y);
#pragma unroll
    for (int j = 0; j < 8; ++j) acc[j] = fmaf(bf2f(h0v[j]), c0, acc[j]);
#pragma unroll
    for (int j = 0; j < 8; ++j) acc[j] = fmaf(bf2f(h1v[j]), c1, acc[j]);
  }
  for (; e < e1; e += 8) {
    const int s = csrsrc[e];
    const float2 p = Pc[s];
    const ushort8 hv = *reinterpret_cast<const ushort8*>(&h[(size_t)s * HDIM + fo]);
    const float c = tanhf(p.x + qd.x) * (p.y * qd.y);
#pragma unroll
    for (int j = 0; j < 8; ++j) acc[j] = fmaf(bf2f(hv[j]), c, acc[j]);
  }
#pragma unroll
  for (int off = 8; off <= 32; off <<= 1) {
#pragma unroll
    for (int j = 0; j < 8; ++j) acc[j] += __shfl_xor(acc[j], off, 64);
  }
  if (grp == 0) {
    ushort8 o;
#pragma unroll
    for (int j = 0; j < 8; ++j) o[j] = f2bf(acc[j]);
    *reinterpret_cast<ushort8*>(&hout[base]) = o;
  }
  if (WNEXT) {
    float psl = 0.f, psr = 0.f;
#pragma unroll
    for (int j = 0; j < 8; ++j) {
      psl = fmaf(acc[j], attl_n[fo + j], psl);
      psr = fmaf(acc[j], attr_n[fo + j], psr);
    }
#pragma unroll
    for (int off = 1; off <= 4; off <<= 1) {
      psl += __shfl_xor(psl, off, 64);
      psr += __shfl_xor(psr, off, 64);
    }
    if (lane == 0) {
      Pn[d] = make_float2(psl, qd.y);
      Qn[d] = make_float2(psr, qd.y);
      Sn[d] = tanhf(psl + psr) * qd.y * qd.y;
    }
  }
}

// ---------------- output: thread-per-node logits + log_softmax ----------------
__global__ __launch_bounds__(256) void k_out(const unsigned short* __restrict__ h,
                                             const float* __restrict__ W2,
                                             const float* __restrict__ b2,
                                             float* __restrict__ out, int nN) {
  __shared__ float w2s[NCLS * HDIM];  // [c][j] row-major
  __shared__ float b2s[NCLS];
  for (int i = threadIdx.x; i < NCLS * HDIM; i += 256) w2s[i] = W2[i];
  if (threadIdx.x < NCLS) b2s[threadIdx.x] = b2[threadIdx.x];
  __syncthreads();
  const int n = blockIdx.x * 256 + threadIdx.x;
  if (n >= nN) return;
  float hr[HDIM];
  const ushort8* hrow = reinterpret_cast<const ushort8*>(&h[(size_t)n * HDIM]);
#pragma unroll
  for (int r = 0; r < 8; ++r) {
    const ushort8 v = hrow[r];
#pragma unroll
    for (int j = 0; j < 8; ++j) hr[r * 8 + j] = bf2f(v[j]);
  }
  const float4* w2s4 = reinterpret_cast<const float4*>(w2s);
  float logits[NCLS];
  float m = -INFINITY;
#pragma unroll
  for (int c = 0; c < NCLS; ++c) {
    float a0 = 0.f, a1 = 0.f, a2 = 0.f, a3 = 0.f;
#pragma unroll
    for (int j4 = 0; j4 < HDIM / 4; j4 += 4) {
      const float4 w0 = w2s4[c * (HDIM / 4) + j4 + 0];
      const float4 w1 = w2s4[c * (HDIM / 4) + j4 + 1];
      const float4 w2v = w2s4[c * (HDIM / 4) + j4 + 2];
      const float4 w3 = w2s4[c * (HDIM / 4) + j4 + 3];
      const int j = j4 * 4;
      a0 = fmaf(hr[j + 0], w0.x, a0);  a0 = fmaf(hr[j + 1], w0.y, a0);
      a0 = fmaf(hr[j + 2], w0.z, a0);  a0 = fmaf(hr[j + 3], w0.w, a0);
      a1 = fmaf(hr[j + 4], w1.x, a1);  a1 = fmaf(hr[j + 5], w1.y, a1);
      a1 = fmaf(hr[j + 6], w1.z, a1);  a1 = fmaf(hr[j + 7], w1.w, a1);
      a2 = fmaf(hr[j + 8], w2v.x, a2); a2 = fmaf(hr[j + 9], w2v.y, a2);
      a2 = fmaf(hr[j + 10], w2v.z, a2); a2 = fmaf(hr[j + 11], w2v.w, a2);
      a3 = fmaf(hr[j + 12], w3.x, a3); a3 = fmaf(hr[j + 13], w3.y, a3);
      a3 = fmaf(hr[j + 14], w3.z, a3); a3 = fmaf(hr[j + 15], w3.w, a3);
    }
    const float lg = (a0 + a1) + (a2 + a3) + b2s[c];
    logits[c] = lg;
    m = fmaxf(m, lg);
  }
  float s = 0.f;
#pragma unroll
  for (int c = 0; c < NCLS; ++c) s += expf(logits[c] - m);
  const float lse = m + logf(s);
  float4* o4 = reinterpret_cast<float4*>(&out[(size_t)n * NCLS]);
#pragma unroll
  for (int c4 = 0; c4 < NCLS / 4; ++c4) {
    float4 o;
    o.x = logits[c4 * 4 + 0] - lse;
    o.y = logits[c4 * 4 + 1] - lse;
    o.z = logits[c4 * 4 + 2] - lse;
    o.w = logits[c4 * 4 + 3] - lse;
    o4[c4] = o;
  }
}

extern "C" void kernel_launch(void* const* d_in, const int* in_sizes, int n_in,
                              void* d_out, int out_size, void* d_ws, size_t ws_size,
                              hipStream_t stream) {
  const float* x = (const float*)d_in[0];
  const int* ei = (const int*)d_in[1];
  const float* W1 = (const float*)d_in[2];
  const float* b1 = (const float*)d_in[3];
  const float* W2 = (const float*)d_in[4];
  const float* b2 = (const float*)d_in[5];
  const float* attl = (const float*)d_in[6];
  const float* attr = (const float*)d_in[7];
  float* out = (float*)d_out;

  const int nN = in_sizes[0] / F_IN;
  const int nE = in_sizes[1] / 2;
  const int* src = ei;
  const int* dst = ei + nE;

  char* w = (char*)d_ws;
  size_t off = 0;
  auto alloc = [&](size_t bytes) {
    void* p = (void*)(w + off);
    off = (off + bytes + 255) & ~(size_t)255;
    return p;
  };
  unsigned short* hraw = (unsigned short*)alloc((size_t)nN * HDIM * 2);
  unsigned short* hA = (unsigned short*)alloc((size_t)nN * HDIM * 2);
  unsigned short* hB = (unsigned short*)alloc((size_t)nN * HDIM * 2);
  float2* P0 = (float2*)alloc((size_t)nN * 8);
  float2* Q0 = (float2*)alloc((size_t)nN * 8);
  float* S0 = (float*)alloc((size_t)nN * 4);
  float2* P1 = (float2*)alloc((size_t)nN * 8);
  float2* Q1 = (float2*)alloc((size_t)nN * 8);
  float* S1 = (float*)alloc((size_t)nN * 4);
  float* al = (float*)alloc((size_t)nN * 4);
  float* ar = (float*)alloc((size_t)nN * 4);
  int* indeg = (int*)alloc((size_t)nN * 4);
  int* rank = (int*)alloc((size_t)nE * 4);
  int* rowptr = (int*)alloc((size_t)(nN + 1) * 4);
  int* csrsrc = (int*)alloc((size_t)nE * 4);
  int* bsum = (int*)alloc(1024);
  int* bpre = (int*)alloc(1024);

  const int nb_n = (nN + 255) / 256;
  const int nb_e = (nE + 255) / 256;
  const int nblk = (nN + 511) / 512;  // 98 <= 128
  const int nb4 = (nN + 3) / 4;

  // lin1 first (independent of graph), fused layer-0 scores
  k_lin1<<<(nN + 63) / 64, 256, 0, stream>>>(x, W1, b1, attl, attr, hraw, al, ar, nN);
  // CSR build (atomic-free scatter, 4B payload)
  k_init<<<nb_n, 256, 0, stream>>>(indeg, nN);
  k_hist<<<nb_e, 256, 0, stream>>>(dst, indeg, rank, nE);
  k_bsum<<<nblk, 256, 0, stream>>>(indeg, bsum, nN);
  k_bscan<<<1, 128, 0, stream>>>(bsum, bpre, rowptr, nblk, nN, nE);
  k_rowptr<<<nblk, 512, 0, stream>>>(indeg, bpre, al, ar, rowptr, P0, Q0, S0, nN);
  k_scatter<<<nb_e, 256, 0, stream>>>(src, dst, rank, rowptr, csrsrc, nE);

  const unsigned short* hin = hraw;
  unsigned short* hout = hA;
  float2 *Pc = P0, *Qc = Q0, *Pn = P1, *Qn = Q1;
  float *Sc = S0, *Sn = S1;
  for (int l = 0; l < NLAYER; ++l) {
    if (l < NLAYER - 1) {
      k_agg<true><<<nb4, 256, 0, stream>>>(hin, hraw, rowptr, csrsrc, Pc, Qc, Sc,
                                           attl + (l + 1) * HDIM, attr + (l + 1) * HDIM,
                                           Pn, Qn, Sn, hout, nN);
    } else {
      k_agg<false><<<nb4, 256, 0, stream>>>(hin, hraw, rowptr, csrsrc, Pc, Qc, Sc,
                                            nullptr, nullptr, Pn, Qn, Sn, hout, nN);
    }
    hin = hout;
    hout = (hout == hA) ? hB : hA;
    float2* tp = Pc; Pc = Pn; Pn = tp;
    float2* tq = Qc; Qc = Qn; Qn = tq;
    float* ts = Sc; Sc = Sn; Sn = ts;
  }
  k_out<<<nb_n, 256, 0, stream>>>(hin, W2, b2, out, nN);
}

// Round 12
// 223.038 us; speedup vs baseline: 1.4795x; 1.0681x over previous
//
#include <hip/hip_runtime.h>

#define F_IN 512
#define HDIM 64
#define NCLS 40
#define NLAYER 4
#define EPS_F 0.2f

typedef __attribute__((ext_vector_type(8))) short short8;
typedef __attribute__((ext_vector_type(4))) float f32x4;
typedef __attribute__((ext_vector_type(8))) unsigned short ushort8;
typedef unsigned long long u64;

__device__ __forceinline__ unsigned short f2bf(float f) {
  unsigned u = __float_as_uint(f);
  u += 0x7FFFu + ((u >> 16) & 1u);  // RNE
  return (unsigned short)(u >> 16);
}
__device__ __forceinline__ float bf2f(unsigned short s) {
  return __uint_as_float(((unsigned)s) << 16);
}
// fast tanh: 1 - 2/(e^{2x}+1); exp inf/0 limits give +-1 correctly
__device__ __forceinline__ float ftanh(float x) {
  float e = __expf(2.0f * x);
  return fmaf(-2.0f, __builtin_amdgcn_rcpf(e + 1.0f), 1.0f);
}

// ---------------- CSR build ----------------
__global__ __launch_bounds__(256) void k_init(int* indeg, int nN) {
  int i = blockIdx.x * 256 + threadIdx.x;
  if (i < nN) indeg[i] = 0;
}

// histogram; the atomic's return value is the edge's rank within its dst row
__global__ __launch_bounds__(256) void k_hist(const int* __restrict__ dst, int* indeg,
                                              int* __restrict__ rank, int nE) {
  int e = blockIdx.x * 256 + threadIdx.x;
  if (e < nE) rank[e] = atomicAdd(&indeg[dst[e]], 1);
}

__global__ __launch_bounds__(256) void k_bsum(const int* __restrict__ indeg, int* bsum, int nN) {
  int i0 = blockIdx.x * 512 + threadIdx.x;
  int v = 0;
  if (i0 < nN) v += indeg[i0];
  if (i0 + 256 < nN) v += indeg[i0 + 256];
#pragma unroll
  for (int off = 32; off > 0; off >>= 1) v += __shfl_xor(v, off, 64);
  __shared__ int s[4];
  if ((threadIdx.x & 63) == 0) s[threadIdx.x >> 6] = v;
  __syncthreads();
  if (threadIdx.x == 0) bsum[blockIdx.x] = s[0] + s[1] + s[2] + s[3];
}

__global__ __launch_bounds__(128) void k_bscan(const int* __restrict__ bsum, int* bpre,
                                               int* rowptr, int nblk, int nN, int nE) {
  __shared__ int sb[128];
  int t = threadIdx.x;
  int v = (t < nblk) ? bsum[t] : 0;
  sb[t] = v;
  __syncthreads();
  int acc = v;
  for (int off = 1; off < 128; off <<= 1) {
    int o = (t >= off) ? sb[t - off] : 0;
    __syncthreads();
    acc += o;
    sb[t] = acc;
    __syncthreads();
  }
  if (t < nblk) bpre[t] = acc - v;
  if (t == 0) rowptr[nN] = nE;
}

// per-chunk scan -> rowptr ; fused per-node finish (P0, Q0, S0) from lin1's al/ar
__global__ __launch_bounds__(512) void k_rowptr(const int* __restrict__ indeg,
                                                const int* __restrict__ bpre,
                                                const float* __restrict__ al,
                                                const float* __restrict__ ar,
                                                int* rowptr,
                                                float2* P, float2* Q, float* selfc, int nN) {
  __shared__ int sb[512];
  int t = threadIdx.x;
  int i = blockIdx.x * 512 + t;
  int v = (i < nN) ? indeg[i] : 0;
  sb[t] = v;
  __syncthreads();
  int acc = v;
  for (int off = 1; off < 512; off <<= 1) {
    int o = (t >= off) ? sb[t - off] : 0;
    __syncthreads();
    acc += o;
    sb[t] = acc;
    __syncthreads();
  }
  if (i < nN) {
    rowptr[i] = bpre[blockIdx.x] + acc - v;
    float dv = rsqrtf((float)v + 1.0f);  // +1 self-loop
    float a = al[i], r = ar[i];
    P[i] = make_float2(a, dv);
    Q[i] = make_float2(r, dv);
    selfc[i] = tanhf(a + r) * dv * dv;
  }
}

// atomic-free scatter: q = rowptr[d] + rank[e]; single 4B src store
__global__ __launch_bounds__(256) void k_scatter(const int* __restrict__ src,
                                                 const int* __restrict__ dst,
                                                 const int* __restrict__ rank,
                                                 const int* __restrict__ rowptr,
                                                 int* __restrict__ csrsrc, int nE) {
  int e = blockIdx.x * 256 + threadIdx.x;
  if (e < nE) {
    int d = dst[e];
    csrsrc[rowptr[d] + rank[e]] = src[e];
  }
}

// ---------------- lin1: hraw = bf16(relu(x @ W1^T + b1)) via bf16 MFMA, fused layer-0 scores ----------------
__global__ __launch_bounds__(256) void k_lin1(const float* __restrict__ x,
                                              const float* __restrict__ W1,
                                              const float* __restrict__ b1,
                                              const float* __restrict__ attl0,
                                              const float* __restrict__ attr0,
                                              unsigned short* __restrict__ hraw,
                                              float* __restrict__ al, float* __restrict__ ar,
                                              int nN) {
  __shared__ unsigned short xs[64 * 64];
  __shared__ unsigned short ws[64 * 64];
  const int t = threadIdx.x;
  const int wv = t >> 6;
  const int l = t & 63;
  const int n0 = blockIdx.x * 64;
  const int srow = t >> 2;
  const int sk4 = (t & 3) * 4;
  const bool xvalid = (n0 + srow) < nN;
  const f32x4* x4 = reinterpret_cast<const f32x4*>(x);
  const f32x4* w4 = reinterpret_cast<const f32x4*>(W1);
  short8* xs8 = reinterpret_cast<short8*>(xs);
  short8* ws8 = reinterpret_cast<short8*>(ws);
  const int wslot0 = srow * 8 + (((t & 3) * 2 + 0) ^ (srow & 7));
  const int wslot1 = srow * 8 + (((t & 3) * 2 + 1) ^ (srow & 7));
  const int arow = l & 15;
  const int kgrp = l >> 4;
  f32x4 acc[4] = {{0.f, 0.f, 0.f, 0.f},
                  {0.f, 0.f, 0.f, 0.f},
                  {0.f, 0.f, 0.f, 0.f},
                  {0.f, 0.f, 0.f, 0.f}};
  f32x4 xa[4], wa[4];
  const f32x4 zero4 = {0.f, 0.f, 0.f, 0.f};
  {
    const size_t xb = (size_t)(n0 + srow) * (F_IN / 4) + sk4;
    const size_t wb = (size_t)srow * (F_IN / 4) + sk4;
#pragma unroll
    for (int r = 0; r < 4; ++r) {
      xa[r] = xvalid ? x4[xb + r] : zero4;
      wa[r] = w4[wb + r];
    }
  }
  for (int c = 0; c < 8; ++c) {
    short8 p0, p1, q0, q1;
#pragma unroll
    for (int r = 0; r < 2; ++r) {
#pragma unroll
      for (int j = 0; j < 4; ++j) {
        p0[r * 4 + j] = (short)f2bf(xa[r][j]);
        p1[r * 4 + j] = (short)f2bf(xa[2 + r][j]);
        q0[r * 4 + j] = (short)f2bf(wa[r][j]);
        q1[r * 4 + j] = (short)f2bf(wa[2 + r][j]);
      }
    }
    xs8[wslot0] = p0;
    xs8[wslot1] = p1;
    ws8[wslot0] = q0;
    ws8[wslot1] = q1;
    __syncthreads();
    if (c < 7) {
      const size_t xb = (size_t)(n0 + srow) * (F_IN / 4) + (c + 1) * 16 + sk4;
      const size_t wb = (size_t)srow * (F_IN / 4) + (c + 1) * 16 + sk4;
#pragma unroll
      for (int r = 0; r < 4; ++r) {
        xa[r] = xvalid ? x4[xb + r] : zero4;
        wa[r] = w4[wb + r];
      }
    }
#pragma unroll
    for (int c2 = 0; c2 < 2; ++c2) {
      const short8 a = xs8[(wv * 16 + arow) * 8 + ((c2 * 4 + kgrp) ^ (arow & 7))];
#pragma unroll
      for (int fs = 0; fs < 4; ++fs) {
        const short8 b = ws8[(fs * 16 + arow) * 8 + ((c2 * 4 + kgrp) ^ (arow & 7))];
        acc[fs] = __builtin_amdgcn_mfma_f32_16x16x32_bf16(a, b, acc[fs], 0, 0, 0);
      }
    }
    __syncthreads();
  }
  // epilogue: relu+bias, bf16 store, fused layer-0 scores
  float psl[4] = {0.f, 0.f, 0.f, 0.f};
  float psr[4] = {0.f, 0.f, 0.f, 0.f};
#pragma unroll
  for (int fs = 0; fs < 4; ++fs) {
    const int feat = fs * 16 + arow;
    const float bias = b1[feat];
    const float atl = attl0[feat];
    const float atr = attr0[feat];
#pragma unroll
    for (int j = 0; j < 4; ++j) {
      const float v = fmaxf(acc[fs][j] + bias, 0.f);
      const int node = n0 + wv * 16 + kgrp * 4 + j;
      if (node < nN) hraw[(size_t)node * HDIM + feat] = f2bf(v);
      psl[j] = fmaf(v, atl, psl[j]);
      psr[j] = fmaf(v, atr, psr[j]);
    }
  }
#pragma unroll
  for (int off = 1; off <= 8; off <<= 1) {
#pragma unroll
    for (int j = 0; j < 4; ++j) {
      psl[j] += __shfl_xor(psl[j], off, 64);
      psr[j] += __shfl_xor(psr[j], off, 64);
    }
  }
  if (arow == 0) {
#pragma unroll
    for (int j = 0; j < 4; ++j) {
      const int node = n0 + wv * 16 + kgrp * 4 + j;
      if (node < nN) {
        al[node] = psl[j];
        ar[node] = psr[j];
      }
    }
  }
}

// ---------------- fused coef+aggregation: wave handles TWO dests, 8 edge-groups x 8 lanes ----------------
// Every iteration issues 2 independent 128B h-gathers (one per dest row) -> steady MLP=2.
template <bool WNEXT>
__global__ __launch_bounds__(256) void k_agg(const unsigned short* __restrict__ h,
                                             const unsigned short* __restrict__ hraw,
                                             const int* __restrict__ rowptr,
                                             const int* __restrict__ csrsrc,
                                             const float2* __restrict__ Pc,
                                             const float2* __restrict__ Qc,
                                             const float* __restrict__ Sc,
                                             const float* __restrict__ attl_n,
                                             const float* __restrict__ attr_n,
                                             float2* __restrict__ Pn, float2* __restrict__ Qn,
                                             float* __restrict__ Sn,
                                             unsigned short* __restrict__ hout, int nN) {
  const int wid = threadIdx.x >> 6, lane = threadIdx.x & 63;
  const int dA = blockIdx.x * 8 + wid * 2;
  if (dA >= nN) return;
  const int dB = dA + 1;
  const bool hasB = dB < nN;
  const int dBs = hasB ? dB : dA;
  const int grp = lane >> 3;
  const int fo = (lane & 7) * 8;
  const size_t baseA = (size_t)dA * HDIM + fo;
  const size_t baseB = (size_t)dBs * HDIM + fo;
  const float2 qdA = Qc[dA];   // {ar_d, dinv_d}
  const float2 qdB = Qc[dBs];
  float accA[8] = {}, accB[8] = {};
  if (grp == 0) {
    const float sc = Sc[dA];
    const ushort8 hd = *reinterpret_cast<const ushort8*>(&h[baseA]);
    const ushort8 rw = *reinterpret_cast<const ushort8*>(&hraw[baseA]);
#pragma unroll
    for (int j = 0; j < 8; ++j) accA[j] = fmaf(bf2f(hd[j]), sc, EPS_F * bf2f(rw[j]));
  } else if (grp == 1 && hasB) {
    const float sc = Sc[dBs];
    const ushort8 hd = *reinterpret_cast<const ushort8*>(&h[baseB]);
    const ushort8 rw = *reinterpret_cast<const ushort8*>(&hraw[baseB]);
#pragma unroll
    for (int j = 0; j < 8; ++j) accB[j] = fmaf(bf2f(hd[j]), sc, EPS_F * bf2f(rw[j]));
  }
  const int r1A = rowptr[dA + 1];
  const int r1B = rowptr[dBs + 1];
  int eA = rowptr[dA] + grp;
  int eB = hasB ? (rowptr[dBs] + grp) : r1B;  // disable B when absent
  while (eA < r1A || eB < r1B) {
    const bool vA = eA < r1A;
    const bool vB = eB < r1B;
    const int sA = csrsrc[vA ? eA : 0];
    const int sB = csrsrc[vB ? eB : 0];
    const float2 pA = Pc[sA];
    const float2 pB = Pc[sB];
    const ushort8 hA = *reinterpret_cast<const ushort8*>(&h[(size_t)sA * HDIM + fo]);
    const ushort8 hB = *reinterpret_cast<const ushort8*>(&h[(size_t)sB * HDIM + fo]);
    const float cA = vA ? ftanh(pA.x + qdA.x) * (pA.y * qdA.y) : 0.f;
    const float cB = vB ? ftanh(pB.x + qdB.x) * (pB.y * qdB.y) : 0.f;
#pragma unroll
    for (int j = 0; j < 8; ++j) accA[j] = fmaf(bf2f(hA[j]), cA, accA[j]);
#pragma unroll
    for (int j = 0; j < 8; ++j) accB[j] = fmaf(bf2f(hB[j]), cB, accB[j]);
    eA += 8;
    eB += 8;
  }
  // reduce across 8 edge-groups (lanes sharing lane&7 hold same feats)
#pragma unroll
  for (int off = 8; off <= 32; off <<= 1) {
#pragma unroll
    for (int j = 0; j < 8; ++j) {
      accA[j] += __shfl_xor(accA[j], off, 64);
      accB[j] += __shfl_xor(accB[j], off, 64);
    }
  }
  if (grp == 0) {
    ushort8 o;
#pragma unroll
    for (int j = 0; j < 8; ++j) o[j] = f2bf(accA[j]);
    *reinterpret_cast<ushort8*>(&hout[baseA]) = o;
  } else if (grp == 1 && hasB) {
    ushort8 o;
#pragma unroll
    for (int j = 0; j < 8; ++j) o[j] = f2bf(accB[j]);
    *reinterpret_cast<ushort8*>(&hout[baseB]) = o;
  }
  if (WNEXT) {
    float pslA = 0.f, psrA = 0.f, pslB = 0.f, psrB = 0.f;
#pragma unroll
    for (int j = 0; j < 8; ++j) {
      const float wl = attl_n[fo + j];
      const float wr = attr_n[fo + j];
      pslA = fmaf(accA[j], wl, pslA);
      psrA = fmaf(accA[j], wr, psrA);
      pslB = fmaf(accB[j], wl, pslB);
      psrB = fmaf(accB[j], wr, psrB);
    }
#pragma unroll
    for (int off = 1; off <= 4; off <<= 1) {
      pslA += __shfl_xor(pslA, off, 64);
      psrA += __shfl_xor(psrA, off, 64);
      pslB += __shfl_xor(pslB, off, 64);
      psrB += __shfl_xor(psrB, off, 64);
    }
    if (lane == 0) {
      Pn[dA] = make_float2(pslA, qdA.y);
      Qn[dA] = make_float2(psrA, qdA.y);
      Sn[dA] = ftanh(pslA + psrA) * qdA.y * qdA.y;
      if (hasB) {
        Pn[dB] = make_float2(pslB, qdB.y);
        Qn[dB] = make_float2(psrB, qdB.y);
        Sn[dB] = ftanh(pslB + psrB) * qdB.y * qdB.y;
      }
    }
  }
}

// ---------------- output: thread-per-node logits + log_softmax ----------------
__global__ __launch_bounds__(256) void k_out(const unsigned short* __restrict__ h,
                                             const float* __restrict__ W2,
                                             const float* __restrict__ b2,
                                             float* __restrict__ out, int nN) {
  __shared__ float w2s[NCLS * HDIM];  // [c][j] row-major
  __shared__ float b2s[NCLS];
  for (int i = threadIdx.x; i < NCLS * HDIM; i += 256) w2s[i] = W2[i];
  if (threadIdx.x < NCLS) b2s[threadIdx.x] = b2[threadIdx.x];
  __syncthreads();
  const int n = blockIdx.x * 256 + threadIdx.x;
  if (n >= nN) return;
  float hr[HDIM];
  const ushort8* hrow = reinterpret_cast<const ushort8*>(&h[(size_t)n * HDIM]);
#pragma unroll
  for (int r = 0; r < 8; ++r) {
    const ushort8 v = hrow[r];
#pragma unroll
    for (int j = 0; j < 8; ++j) hr[r * 8 + j] = bf2f(v[j]);
  }
  const float4* w2s4 = reinterpret_cast<const float4*>(w2s);
  float logits[NCLS];
  float m = -INFINITY;
#pragma unroll
  for (int c = 0; c < NCLS; ++c) {
    float a0 = 0.f, a1 = 0.f, a2 = 0.f, a3 = 0.f;
#pragma unroll
    for (int j4 = 0; j4 < HDIM / 4; j4 += 4) {
      const float4 w0 = w2s4[c * (HDIM / 4) + j4 + 0];
      const float4 w1 = w2s4[c * (HDIM / 4) + j4 + 1];
      const float4 w2v = w2s4[c * (HDIM / 4) + j4 + 2];
      const float4 w3 = w2s4[c * (HDIM / 4) + j4 + 3];
      const int j = j4 * 4;
      a0 = fmaf(hr[j + 0], w0.x, a0);  a0 = fmaf(hr[j + 1], w0.y, a0);
      a0 = fmaf(hr[j + 2], w0.z, a0);  a0 = fmaf(hr[j + 3], w0.w, a0);
      a1 = fmaf(hr[j + 4], w1.x, a1);  a1 = fmaf(hr[j + 5], w1.y, a1);
      a1 = fmaf(hr[j + 6], w1.z, a1);  a1 = fmaf(hr[j + 7], w1.w, a1);
      a2 = fmaf(hr[j + 8], w2v.x, a2); a2 = fmaf(hr[j + 9], w2v.y, a2);
      a2 = fmaf(hr[j + 10], w2v.z, a2); a2 = fmaf(hr[j + 11], w2v.w, a2);
      a3 = fmaf(hr[j + 12], w3.x, a3); a3 = fmaf(hr[j + 13], w3.y, a3);
      a3 = fmaf(hr[j + 14], w3.z, a3); a3 = fmaf(hr[j + 15], w3.w, a3);
    }
    const float lg = (a0 + a1) + (a2 + a3) + b2s[c];
    logits[c] = lg;
    m = fmaxf(m, lg);
  }
  float s = 0.f;
#pragma unroll
  for (int c = 0; c < NCLS; ++c) s += expf(logits[c] - m);
  const float lse = m + logf(s);
  float4* o4 = reinterpret_cast<float4*>(&out[(size_t)n * NCLS]);
#pragma unroll
  for (int c4 = 0; c4 < NCLS / 4; ++c4) {
    float4 o;
    o.x = logits[c4 * 4 + 0] - lse;
    o.y = logits[c4 * 4 + 1] - lse;
    o.z = logits[c4 * 4 + 2] - lse;
    o.w = logits[c4 * 4 + 3] - lse;
    o4[c4] = o;
  }
}

extern "C" void kernel_launch(void* const* d_in, const int* in_sizes, int n_in,
                              void* d_out, int out_size, void* d_ws, size_t ws_size,
                              hipStream_t stream) {
  const float* x = (const float*)d_in[0];
  const int* ei = (const int*)d_in[1];
  const float* W1 = (const float*)d_in[2];
  const float* b1 = (const float*)d_in[3];
  const float* W2 = (const float*)d_in[4];
  const float* b2 = (const float*)d_in[5];
  const float* attl = (const float*)d_in[6];
  const float* attr = (const float*)d_in[7];
  float* out = (float*)d_out;

  const int nN = in_sizes[0] / F_IN;
  const int nE = in_sizes[1] / 2;
  const int* src = ei;
  const int* dst = ei + nE;

  char* w = (char*)d_ws;
  size_t off = 0;
  auto alloc = [&](size_t bytes) {
    void* p = (void*)(w + off);
    off = (off + bytes + 255) & ~(size_t)255;
    return p;
  };
  unsigned short* hraw = (unsigned short*)alloc((size_t)nN * HDIM * 2);
  unsigned short* hA = (unsigned short*)alloc((size_t)nN * HDIM * 2);
  unsigned short* hB = (unsigned short*)alloc((size_t)nN * HDIM * 2);
  float2* P0 = (float2*)alloc((size_t)nN * 8);
  float2* Q0 = (float2*)alloc((size_t)nN * 8);
  float* S0 = (float*)alloc((size_t)nN * 4);
  float2* P1 = (float2*)alloc((size_t)nN * 8);
  float2* Q1 = (float2*)alloc((size_t)nN * 8);
  float* S1 = (float*)alloc((size_t)nN * 4);
  float* al = (float*)alloc((size_t)nN * 4);
  float* ar = (float*)alloc((size_t)nN * 4);
  int* indeg = (int*)alloc((size_t)nN * 4);
  int* rank = (int*)alloc((size_t)nE * 4);
  int* rowptr = (int*)alloc((size_t)(nN + 1) * 4);
  int* csrsrc = (int*)alloc((size_t)nE * 4);
  int* bsum = (int*)alloc(1024);
  int* bpre = (int*)alloc(1024);

  const int nb_n = (nN + 255) / 256;
  const int nb_e = (nE + 255) / 256;
  const int nblk = (nN + 511) / 512;  // 98 <= 128
  const int nb8 = (nN + 7) / 8;

  // lin1 first (independent of graph), fused layer-0 scores
  k_lin1<<<(nN + 63) / 64, 256, 0, stream>>>(x, W1, b1, attl, attr, hraw, al, ar, nN);
  // CSR build (atomic-free scatter, 4B payload)
  k_init<<<nb_n, 256, 0, stream>>>(indeg, nN);
  k_hist<<<nb_e, 256, 0, stream>>>(dst, indeg, rank, nE);
  k_bsum<<<nblk, 256, 0, stream>>>(indeg, bsum, nN);
  k_bscan<<<1, 128, 0, stream>>>(bsum, bpre, rowptr, nblk, nN, nE);
  k_rowptr<<<nblk, 512, 0, stream>>>(indeg, bpre, al, ar, rowptr, P0, Q0, S0, nN);
  k_scatter<<<nb_e, 256, 0, stream>>>(src, dst, rank, rowptr, csrsrc, nE);

  const unsigned short* hin = hraw;
  unsigned short* hout = hA;
  float2 *Pc = P0, *Qc = Q0, *Pn = P1, *Qn = Q1;
  float *Sc = S0, *Sn = S1;
  for (int l = 0; l < NLAYER; ++l) {
    if (l < NLAYER - 1) {
      k_agg<true><<<nb8, 256, 0, stream>>>(hin, hraw, rowptr, csrsrc, Pc, Qc, Sc,
                                           attl + (l + 1) * HDIM, attr + (l + 1) * HDIM,
                                           Pn, Qn, Sn, hout, nN);
    } else {
      k_agg<false><<<nb8, 256, 0, stream>>>(hin, hraw, rowptr, csrsrc, Pc, Qc, Sc,
                                            nullptr, nullptr, Pn, Qn, Sn, hout, nN);
    }
    hin = hout;
    hout = (hout == hA) ? hB : hA;
    float2* tp = Pc; Pc = Pn; Pn = tp;
    float2* tq = Qc; Qc = Qn; Qn = tq;
    float* ts = Sc; Sc = Sn; Sn = ts;
  }
  k_out<<<nb_n, 256, 0, stream>>>(hin, W2, b2, out, nN);
}

// Round 13
// 217.521 us; speedup vs baseline: 1.5170x; 1.0254x over previous
//
#include <hip/hip_runtime.h>

#define F_IN 512
#define HDIM 64
#define NCLS 40
#define NLAYER 4
#define EPS_F 0.2f

typedef __attribute__((ext_vector_type(8))) short short8;
typedef __attribute__((ext_vector_type(4))) float f32x4;
typedef __attribute__((ext_vector_type(8))) unsigned short ushort8;
typedef unsigned long long u64;

__device__ __forceinline__ unsigned short f2bf(float f) {
  unsigned u = __float_as_uint(f);
  u += 0x7FFFu + ((u >> 16) & 1u);  // RNE
  return (unsigned short)(u >> 16);
}
__device__ __forceinline__ float bf2f(unsigned short s) {
  return __uint_as_float(((unsigned)s) << 16);
}
// fast tanh: 1 - 2/(e^{2x}+1); exp inf/0 limits give +-1 correctly
__device__ __forceinline__ float ftanh(float x) {
  float e = __expf(2.0f * x);
  return fmaf(-2.0f, __builtin_amdgcn_rcpf(e + 1.0f), 1.0f);
}

// ---------------- CSR build ----------------
__global__ __launch_bounds__(256) void k_init(int* indeg, int nN) {
  int i = blockIdx.x * 256 + threadIdx.x;
  if (i < nN) indeg[i] = 0;
}

// histogram; the atomic's return value is the edge's rank within its dst row
__global__ __launch_bounds__(256) void k_hist(const int* __restrict__ dst, int* indeg,
                                              int* __restrict__ rank, int nE) {
  int e = blockIdx.x * 256 + threadIdx.x;
  if (e < nE) rank[e] = atomicAdd(&indeg[dst[e]], 1);
}

__global__ __launch_bounds__(256) void k_bsum(const int* __restrict__ indeg, int* bsum, int nN) {
  int i0 = blockIdx.x * 512 + threadIdx.x;
  int v = 0;
  if (i0 < nN) v += indeg[i0];
  if (i0 + 256 < nN) v += indeg[i0 + 256];
#pragma unroll
  for (int off = 32; off > 0; off >>= 1) v += __shfl_xor(v, off, 64);
  __shared__ int s[4];
  if ((threadIdx.x & 63) == 0) s[threadIdx.x >> 6] = v;
  __syncthreads();
  if (threadIdx.x == 0) bsum[blockIdx.x] = s[0] + s[1] + s[2] + s[3];
}

__global__ __launch_bounds__(128) void k_bscan(const int* __restrict__ bsum, int* bpre,
                                               int* rowptr, int nblk, int nN, int nE) {
  __shared__ int sb[128];
  int t = threadIdx.x;
  int v = (t < nblk) ? bsum[t] : 0;
  sb[t] = v;
  __syncthreads();
  int acc = v;
  for (int off = 1; off < 128; off <<= 1) {
    int o = (t >= off) ? sb[t - off] : 0;
    __syncthreads();
    acc += o;
    sb[t] = acc;
    __syncthreads();
  }
  if (t < nblk) bpre[t] = acc - v;
  if (t == 0) rowptr[nN] = nE;
}

// per-chunk scan -> rowptr ; fused per-node finish (P0, Q0, S0) from lin1's al/ar
__global__ __launch_bounds__(512) void k_rowptr(const int* __restrict__ indeg,
                                                const int* __restrict__ bpre,
                                                const float* __restrict__ al,
                                                const float* __restrict__ ar,
                                                int* rowptr,
                                                float2* P, float2* Q, float* selfc, int nN) {
  __shared__ int sb[512];
  int t = threadIdx.x;
  int i = blockIdx.x * 512 + t;
  int v = (i < nN) ? indeg[i] : 0;
  sb[t] = v;
  __syncthreads();
  int acc = v;
  for (int off = 1; off < 512; off <<= 1) {
    int o = (t >= off) ? sb[t - off] : 0;
    __syncthreads();
    acc += o;
    sb[t] = acc;
    __syncthreads();
  }
  if (i < nN) {
    rowptr[i] = bpre[blockIdx.x] + acc - v;
    float dv = rsqrtf((float)v + 1.0f);  // +1 self-loop
    float a = al[i], r = ar[i];
    P[i] = make_float2(a, dv);
    Q[i] = make_float2(r, dv);
    selfc[i] = tanhf(a + r) * dv * dv;
  }
}

// atomic-free scatter: q = rowptr[d] + rank[e]; single 4B src store
__global__ __launch_bounds__(256) void k_scatter(const int* __restrict__ src,
                                                 const int* __restrict__ dst,
                                                 const int* __restrict__ rank,
                                                 const int* __restrict__ rowptr,
                                                 int* __restrict__ csrsrc, int nE) {
  int e = blockIdx.x * 256 + threadIdx.x;
  if (e < nE) {
    int d = dst[e];
    csrsrc[rowptr[d] + rank[e]] = src[e];
  }
}

// ---------------- lin1: hraw = bf16(relu(x @ W1^T + b1)) via bf16 MFMA, fused layer-0 scores ----------------
__global__ __launch_bounds__(256) void k_lin1(const float* __restrict__ x,
                                              const float* __restrict__ W1,
                                              const float* __restrict__ b1,
                                              const float* __restrict__ attl0,
                                              const float* __restrict__ attr0,
                                              unsigned short* __restrict__ hraw,
                                              float* __restrict__ al, float* __restrict__ ar,
                                              int nN) {
  __shared__ unsigned short xs[64 * 64];
  __shared__ unsigned short ws[64 * 64];
  const int t = threadIdx.x;
  const int wv = t >> 6;
  const int l = t & 63;
  const int n0 = blockIdx.x * 64;
  const int srow = t >> 2;
  const int sk4 = (t & 3) * 4;
  const bool xvalid = (n0 + srow) < nN;
  const f32x4* x4 = reinterpret_cast<const f32x4*>(x);
  const f32x4* w4 = reinterpret_cast<const f32x4*>(W1);
  short8* xs8 = reinterpret_cast<short8*>(xs);
  short8* ws8 = reinterpret_cast<short8*>(ws);
  const int wslot0 = srow * 8 + (((t & 3) * 2 + 0) ^ (srow & 7));
  const int wslot1 = srow * 8 + (((t & 3) * 2 + 1) ^ (srow & 7));
  const int arow = l & 15;
  const int kgrp = l >> 4;
  f32x4 acc[4] = {{0.f, 0.f, 0.f, 0.f},
                  {0.f, 0.f, 0.f, 0.f},
                  {0.f, 0.f, 0.f, 0.f},
                  {0.f, 0.f, 0.f, 0.f}};
  f32x4 xa[4], wa[4];
  const f32x4 zero4 = {0.f, 0.f, 0.f, 0.f};
  {
    const size_t xb = (size_t)(n0 + srow) * (F_IN / 4) + sk4;
    const size_t wb = (size_t)srow * (F_IN / 4) + sk4;
#pragma unroll
    for (int r = 0; r < 4; ++r) {
      xa[r] = xvalid ? x4[xb + r] : zero4;
      wa[r] = w4[wb + r];
    }
  }
  for (int c = 0; c < 8; ++c) {
    short8 p0, p1, q0, q1;
#pragma unroll
    for (int r = 0; r < 2; ++r) {
#pragma unroll
      for (int j = 0; j < 4; ++j) {
        p0[r * 4 + j] = (short)f2bf(xa[r][j]);
        p1[r * 4 + j] = (short)f2bf(xa[2 + r][j]);
        q0[r * 4 + j] = (short)f2bf(wa[r][j]);
        q1[r * 4 + j] = (short)f2bf(wa[2 + r][j]);
      }
    }
    xs8[wslot0] = p0;
    xs8[wslot1] = p1;
    ws8[wslot0] = q0;
    ws8[wslot1] = q1;
    __syncthreads();
    if (c < 7) {
      const size_t xb = (size_t)(n0 + srow) * (F_IN / 4) + (c + 1) * 16 + sk4;
      const size_t wb = (size_t)srow * (F_IN / 4) + (c + 1) * 16 + sk4;
#pragma unroll
      for (int r = 0; r < 4; ++r) {
        xa[r] = xvalid ? x4[xb + r] : zero4;
        wa[r] = w4[wb + r];
      }
    }
#pragma unroll
    for (int c2 = 0; c2 < 2; ++c2) {
      const short8 a = xs8[(wv * 16 + arow) * 8 + ((c2 * 4 + kgrp) ^ (arow & 7))];
#pragma unroll
      for (int fs = 0; fs < 4; ++fs) {
        const short8 b = ws8[(fs * 16 + arow) * 8 + ((c2 * 4 + kgrp) ^ (arow & 7))];
        acc[fs] = __builtin_amdgcn_mfma_f32_16x16x32_bf16(a, b, acc[fs], 0, 0, 0);
      }
    }
    __syncthreads();
  }
  // epilogue: relu+bias, bf16 store, fused layer-0 scores
  float psl[4] = {0.f, 0.f, 0.f, 0.f};
  float psr[4] = {0.f, 0.f, 0.f, 0.f};
#pragma unroll
  for (int fs = 0; fs < 4; ++fs) {
    const int feat = fs * 16 + arow;
    const float bias = b1[feat];
    const float atl = attl0[feat];
    const float atr = attr0[feat];
#pragma unroll
    for (int j = 0; j < 4; ++j) {
      const float v = fmaxf(acc[fs][j] + bias, 0.f);
      const int node = n0 + wv * 16 + kgrp * 4 + j;
      if (node < nN) hraw[(size_t)node * HDIM + feat] = f2bf(v);
      psl[j] = fmaf(v, atl, psl[j]);
      psr[j] = fmaf(v, atr, psr[j]);
    }
  }
#pragma unroll
  for (int off = 1; off <= 8; off <<= 1) {
#pragma unroll
    for (int j = 0; j < 4; ++j) {
      psl[j] += __shfl_xor(psl[j], off, 64);
      psr[j] += __shfl_xor(psr[j], off, 64);
    }
  }
  if (arow == 0) {
#pragma unroll
    for (int j = 0; j < 4; ++j) {
      const int node = n0 + wv * 16 + kgrp * 4 + j;
      if (node < nN) {
        al[node] = psl[j];
        ar[node] = psr[j];
      }
    }
  }
}

// ---------------- fused coef+aggregation: 2 dests/wave, software-pipelined index stream ----------------
// Next iteration's csrsrc load issues alongside the current h/P gathers -> index latency hidden.
template <bool WNEXT>
__global__ __launch_bounds__(256) void k_agg(const unsigned short* __restrict__ h,
                                             const unsigned short* __restrict__ hraw,
                                             const int* __restrict__ rowptr,
                                             const int* __restrict__ csrsrc,
                                             const float2* __restrict__ Pc,
                                             const float2* __restrict__ Qc,
                                             const float* __restrict__ Sc,
                                             const float* __restrict__ attl_n,
                                             const float* __restrict__ attr_n,
                                             float2* __restrict__ Pn, float2* __restrict__ Qn,
                                             float* __restrict__ Sn,
                                             unsigned short* __restrict__ hout, int nN) {
  const int wid = threadIdx.x >> 6, lane = threadIdx.x & 63;
  const int dA = blockIdx.x * 8 + wid * 2;
  if (dA >= nN) return;
  const int dB = dA + 1;
  const bool hasB = dB < nN;
  const int dBs = hasB ? dB : dA;
  const int grp = lane >> 3;
  const int fo = (lane & 7) * 8;
  const size_t baseA = (size_t)dA * HDIM + fo;
  const size_t baseB = (size_t)dBs * HDIM + fo;
  const float2 qdA = Qc[dA];   // {ar_d, dinv_d}
  const float2 qdB = Qc[dBs];
  float accA[8] = {}, accB[8] = {};
  if (grp == 0) {
    const float sc = Sc[dA];
    const ushort8 hd = *reinterpret_cast<const ushort8*>(&h[baseA]);
    const ushort8 rw = *reinterpret_cast<const ushort8*>(&hraw[baseA]);
#pragma unroll
    for (int j = 0; j < 8; ++j) accA[j] = fmaf(bf2f(hd[j]), sc, EPS_F * bf2f(rw[j]));
  } else if (grp == 1 && hasB) {
    const float sc = Sc[dBs];
    const ushort8 hd = *reinterpret_cast<const ushort8*>(&h[baseB]);
    const ushort8 rw = *reinterpret_cast<const ushort8*>(&hraw[baseB]);
#pragma unroll
    for (int j = 0; j < 8; ++j) accB[j] = fmaf(bf2f(hd[j]), sc, EPS_F * bf2f(rw[j]));
  }
  const int r1A = rowptr[dA + 1];
  const int r1B = rowptr[dBs + 1];
  int eA = rowptr[dA] + grp;
  int eB = hasB ? (rowptr[dBs] + grp) : r1B;  // disable B when absent
  // prime the index pipeline
  int sA = csrsrc[(eA < r1A) ? eA : 0];
  int sB = csrsrc[(eB < r1B) ? eB : 0];
  while (eA < r1A || eB < r1B) {
    const bool vA = eA < r1A;
    const bool vB = eB < r1B;
    // gathers for CURRENT edges (sA/sB already resident)
    const float2 pA = Pc[sA];
    const float2 pB = Pc[sB];
    const ushort8 hA = *reinterpret_cast<const ushort8*>(&h[(size_t)sA * HDIM + fo]);
    const ushort8 hB = *reinterpret_cast<const ushort8*>(&h[(size_t)sB * HDIM + fo]);
    // prefetch NEXT indices (independent of the gathers above)
    const int eA2 = eA + 8;
    const int eB2 = eB + 8;
    const int sA2 = csrsrc[(eA2 < r1A) ? eA2 : 0];
    const int sB2 = csrsrc[(eB2 < r1B) ? eB2 : 0];
    const float cA = vA ? ftanh(pA.x + qdA.x) * (pA.y * qdA.y) : 0.f;
    const float cB = vB ? ftanh(pB.x + qdB.x) * (pB.y * qdB.y) : 0.f;
#pragma unroll
    for (int j = 0; j < 8; ++j) accA[j] = fmaf(bf2f(hA[j]), cA, accA[j]);
#pragma unroll
    for (int j = 0; j < 8; ++j) accB[j] = fmaf(bf2f(hB[j]), cB, accB[j]);
    eA = eA2;
    eB = eB2;
    sA = sA2;
    sB = sB2;
  }
  // reduce across 8 edge-groups (lanes sharing lane&7 hold same feats)
#pragma unroll
  for (int off = 8; off <= 32; off <<= 1) {
#pragma unroll
    for (int j = 0; j < 8; ++j) {
      accA[j] += __shfl_xor(accA[j], off, 64);
      accB[j] += __shfl_xor(accB[j], off, 64);
    }
  }
  if (grp == 0) {
    ushort8 o;
#pragma unroll
    for (int j = 0; j < 8; ++j) o[j] = f2bf(accA[j]);
    *reinterpret_cast<ushort8*>(&hout[baseA]) = o;
  } else if (grp == 1 && hasB) {
    ushort8 o;
#pragma unroll
    for (int j = 0; j < 8; ++j) o[j] = f2bf(accB[j]);
    *reinterpret_cast<ushort8*>(&hout[baseB]) = o;
  }
  if (WNEXT) {
    float pslA = 0.f, psrA = 0.f, pslB = 0.f, psrB = 0.f;
#pragma unroll
    for (int j = 0; j < 8; ++j) {
      const float wl = attl_n[fo + j];
      const float wr = attr_n[fo + j];
      pslA = fmaf(accA[j], wl, pslA);
      psrA = fmaf(accA[j], wr, psrA);
      pslB = fmaf(accB[j], wl, pslB);
      psrB = fmaf(accB[j], wr, psrB);
    }
#pragma unroll
    for (int off = 1; off <= 4; off <<= 1) {
      pslA += __shfl_xor(pslA, off, 64);
      psrA += __shfl_xor(psrA, off, 64);
      pslB += __shfl_xor(pslB, off, 64);
      psrB += __shfl_xor(psrB, off, 64);
    }
    if (lane == 0) {
      Pn[dA] = make_float2(pslA, qdA.y);
      Qn[dA] = make_float2(psrA, qdA.y);
      Sn[dA] = ftanh(pslA + psrA) * qdA.y * qdA.y;
      if (hasB) {
        Pn[dB] = make_float2(pslB, qdB.y);
        Qn[dB] = make_float2(psrB, qdB.y);
        Sn[dB] = ftanh(pslB + psrB) * qdB.y * qdB.y;
      }
    }
  }
}

// ---------------- output: thread-per-node logits + log_softmax ----------------
__global__ __launch_bounds__(256) void k_out(const unsigned short* __restrict__ h,
                                             const float* __restrict__ W2,
                                             const float* __restrict__ b2,
                                             float* __restrict__ out, int nN) {
  __shared__ float w2s[NCLS * HDIM];  // [c][j] row-major
  __shared__ float b2s[NCLS];
  for (int i = threadIdx.x; i < NCLS * HDIM; i += 256) w2s[i] = W2[i];
  if (threadIdx.x < NCLS) b2s[threadIdx.x] = b2[threadIdx.x];
  __syncthreads();
  const int n = blockIdx.x * 256 + threadIdx.x;
  if (n >= nN) return;
  float hr[HDIM];
  const ushort8* hrow = reinterpret_cast<const ushort8*>(&h[(size_t)n * HDIM]);
#pragma unroll
  for (int r = 0; r < 8; ++r) {
    const ushort8 v = hrow[r];
#pragma unroll
    for (int j = 0; j < 8; ++j) hr[r * 8 + j] = bf2f(v[j]);
  }
  const float4* w2s4 = reinterpret_cast<const float4*>(w2s);
  float logits[NCLS];
  float m = -INFINITY;
#pragma unroll
  for (int c = 0; c < NCLS; ++c) {
    float a0 = 0.f, a1 = 0.f, a2 = 0.f, a3 = 0.f;
#pragma unroll
    for (int j4 = 0; j4 < HDIM / 4; j4 += 4) {
      const float4 w0 = w2s4[c * (HDIM / 4) + j4 + 0];
      const float4 w1 = w2s4[c * (HDIM / 4) + j4 + 1];
      const float4 w2v = w2s4[c * (HDIM / 4) + j4 + 2];
      const float4 w3 = w2s4[c * (HDIM / 4) + j4 + 3];
      const int j = j4 * 4;
      a0 = fmaf(hr[j + 0], w0.x, a0);  a0 = fmaf(hr[j + 1], w0.y, a0);
      a0 = fmaf(hr[j + 2], w0.z, a0);  a0 = fmaf(hr[j + 3], w0.w, a0);
      a1 = fmaf(hr[j + 4], w1.x, a1);  a1 = fmaf(hr[j + 5], w1.y, a1);
      a1 = fmaf(hr[j + 6], w1.z, a1);  a1 = fmaf(hr[j + 7], w1.w, a1);
      a2 = fmaf(hr[j + 8], w2v.x, a2); a2 = fmaf(hr[j + 9], w2v.y, a2);
      a2 = fmaf(hr[j + 10], w2v.z, a2); a2 = fmaf(hr[j + 11], w2v.w, a2);
      a3 = fmaf(hr[j + 12], w3.x, a3); a3 = fmaf(hr[j + 13], w3.y, a3);
      a3 = fmaf(hr[j + 14], w3.z, a3); a3 = fmaf(hr[j + 15], w3.w, a3);
    }
    const float lg = (a0 + a1) + (a2 + a3) + b2s[c];
    logits[c] = lg;
    m = fmaxf(m, lg);
  }
  float s = 0.f;
#pragma unroll
  for (int c = 0; c < NCLS; ++c) s += expf(logits[c] - m);
  const float lse = m + logf(s);
  float4* o4 = reinterpret_cast<float4*>(&out[(size_t)n * NCLS]);
#pragma unroll
  for (int c4 = 0; c4 < NCLS / 4; ++c4) {
    float4 o;
    o.x = logits[c4 * 4 + 0] - lse;
    o.y = logits[c4 * 4 + 1] - lse;
    o.z = logits[c4 * 4 + 2] - lse;
    o.w = logits[c4 * 4 + 3] - lse;
    o4[c4] = o;
  }
}

extern "C" void kernel_launch(void* const* d_in, const int* in_sizes, int n_in,
                              void* d_out, int out_size, void* d_ws, size_t ws_size,
                              hipStream_t stream) {
  const float* x = (const float*)d_in[0];
  const int* ei = (const int*)d_in[1];
  const float* W1 = (const float*)d_in[2];
  const float* b1 = (const float*)d_in[3];
  const float* W2 = (const float*)d_in[4];
  const float* b2 = (const float*)d_in[5];
  const float* attl = (const float*)d_in[6];
  const float* attr = (const float*)d_in[7];
  float* out = (float*)d_out;

  const int nN = in_sizes[0] / F_IN;
  const int nE = in_sizes[1] / 2;
  const int* src = ei;
  const int* dst = ei + nE;

  char* w = (char*)d_ws;
  size_t off = 0;
  auto alloc = [&](size_t bytes) {
    void* p = (void*)(w + off);
    off = (off + bytes + 255) & ~(size_t)255;
    return p;
  };
  unsigned short* hraw = (unsigned short*)alloc((size_t)nN * HDIM * 2);
  unsigned short* hA = (unsigned short*)alloc((size_t)nN * HDIM * 2);
  unsigned short* hB = (unsigned short*)alloc((size_t)nN * HDIM * 2);
  float2* P0 = (float2*)alloc((size_t)nN * 8);
  float2* Q0 = (float2*)alloc((size_t)nN * 8);
  float* S0 = (float*)alloc((size_t)nN * 4);
  float2* P1 = (float2*)alloc((size_t)nN * 8);
  float2* Q1 = (float2*)alloc((size_t)nN * 8);
  float* S1 = (float*)alloc((size_t)nN * 4);
  float* al = (float*)alloc((size_t)nN * 4);
  float* ar = (float*)alloc((size_t)nN * 4);
  int* indeg = (int*)alloc((size_t)nN * 4);
  int* rank = (int*)alloc((size_t)nE * 4);
  int* rowptr = (int*)alloc((size_t)(nN + 1) * 4);
  int* csrsrc = (int*)alloc((size_t)nE * 4);
  int* bsum = (int*)alloc(1024);
  int* bpre = (int*)alloc(1024);

  const int nb_n = (nN + 255) / 256;
  const int nb_e = (nE + 255) / 256;
  const int nblk = (nN + 511) / 512;  // 98 <= 128
  const int nb8 = (nN + 7) / 8;

  // lin1 first (independent of graph), fused layer-0 scores
  k_lin1<<<(nN + 63) / 64, 256, 0, stream>>>(x, W1, b1, attl, attr, hraw, al, ar, nN);
  // CSR build (atomic-free scatter, 4B payload)
  k_init<<<nb_n, 256, 0, stream>>>(indeg, nN);
  k_hist<<<nb_e, 256, 0, stream>>>(dst, indeg, rank, nE);
  k_bsum<<<nblk, 256, 0, stream>>>(indeg, bsum, nN);
  k_bscan<<<1, 128, 0, stream>>>(bsum, bpre, rowptr, nblk, nN, nE);
  k_rowptr<<<nblk, 512, 0, stream>>>(indeg, bpre, al, ar, rowptr, P0, Q0, S0, nN);
  k_scatter<<<nb_e, 256, 0, stream>>>(src, dst, rank, rowptr, csrsrc, nE);

  const unsigned short* hin = hraw;
  unsigned short* hout = hA;
  float2 *Pc = P0, *Qc = Q0, *Pn = P1, *Qn = Q1;
  float *Sc = S0, *Sn = S1;
  for (int l = 0; l < NLAYER; ++l) {
    if (l < NLAYER - 1) {
      k_agg<true><<<nb8, 256, 0, stream>>>(hin, hraw, rowptr, csrsrc, Pc, Qc, Sc,
                                           attl + (l + 1) * HDIM, attr + (l + 1) * HDIM,
                                           Pn, Qn, Sn, hout, nN);
    } else {
      k_agg<false><<<nb8, 256, 0, stream>>>(hin, hraw, rowptr, csrsrc, Pc, Qc, Sc,
                                            nullptr, nullptr, Pn, Qn, Sn, hout, nN);
    }
    hin = hout;
    hout = (hout == hA) ? hB : hA;
    float2* tp = Pc; Pc = Pn; Pn = tp;
    float2* tq = Qc; Qc = Qn; Qn = tq;
    float* ts = Sc; Sc = Sn; Sn = ts;
  }
  k_out<<<nb_n, 256, 0, stream>>>(hin, W2, b2, out, nN);
}